// Round 16
// baseline (182.830 us; speedup 1.0000x reference)
//
#include <hip/hip_runtime.h>

#define HD 128
#define LSEQ 200
#define BATCH 2048
#define NE 8
#define SWH 64

#define BM 32        // tokens per tile
#define LDX 136      // padded bf16 row stride for x tile
#define LDH 264      // padded bf16 row stride for hidden tile
#define LDO 132      // padded f32 row stride for out tile
#define NTILES ((BATCH * LSEQ) / BM)   // 12800
#define GRID 512     // persistent: 2 blocks/CU (512 threads -> 16 waves/CU)

typedef float f32x4 __attribute__((ext_vector_type(4)));
typedef __bf16 bf16x4 __attribute__((ext_vector_type(4)));
typedef __bf16 bf16x8 __attribute__((ext_vector_type(8)));

// Raw barrier: per-wave LDS drain + s_barrier, no vmcnt(0) drain.
#define BAR() do {                                          \
    asm volatile("s_waitcnt lgkmcnt(0)" ::: "memory");      \
    __builtin_amdgcn_sched_barrier(0);                      \
    __builtin_amdgcn_s_barrier();                           \
    __builtin_amdgcn_sched_barrier(0);                      \
} while (0)

static __device__ __forceinline__ unsigned short f2bf(float f) {
    union { float f; unsigned u; } v; v.f = f;
    unsigned u = v.u;
    u += 0x7fffu + ((u >> 16) & 1u);   // round-to-nearest-even
    return (unsigned short)(u >> 16);
}

// ---------------- fused routing + weight prep (R8 version, verbatim) ----------------
// W1c [256][128]: rows 0-127 = uW1, rows 128-255 = eW1[route]
// W2c [128][256]: cols 0-127 = uW2, cols 128-255 = eW2[route]
__global__ void prep_route(const float* __restrict__ x_real,
                           const float* __restrict__ sW1, const float* __restrict__ sb1,
                           const float* __restrict__ sW2, const float* __restrict__ sb2,
                           const float* __restrict__ uW1, const float* __restrict__ ub1,
                           const float* __restrict__ uW2, const float* __restrict__ ub2,
                           const float* __restrict__ eW1, const float* __restrict__ eb1,
                           const float* __restrict__ eW2, const float* __restrict__ eb2,
                           float* __restrict__ out_tail,
                           unsigned short* __restrict__ W1c, unsigned short* __restrict__ W2c,
                           float* __restrict__ b1c, float* __restrict__ b2s) {
    __shared__ float part[256];
    __shared__ float xm[HD];
    __shared__ float hsw[SWH];
    __shared__ float logits[NE];
    __shared__ int route_s;
    const int t = threadIdx.x;   // 256 threads

    {
        int col = t & 127, half = t >> 7;
        float s = 0.f;
        for (int l = half * 100; l < half * 100 + 100; ++l) s += x_real[l * HD + col];
        part[t] = s;
    }
    __syncthreads();
    if (t < HD) xm[t] = (part[t] + part[t + 128]) * (1.0f / LSEQ);
    __syncthreads();
    if (t < SWH) {
        float s = sb1[t];
        for (int k = 0; k < HD; ++k) s += xm[k] * sW1[t * HD + k];
        hsw[t] = s > 0.f ? s : 0.f;
    }
    __syncthreads();
    if (t < NE) {
        float s = sb2[t];
        for (int k = 0; k < SWH; ++k) s += hsw[k] * sW2[t * SWH + k];
        logits[t] = s;
    }
    __syncthreads();
    if (t == 0) {
        float mx = logits[0]; int am = 0;
        for (int e = 1; e < NE; ++e) if (logits[e] > mx) { mx = logits[e]; am = e; }
        float den = 0.f;
        for (int e = 0; e < NE; ++e) den += __expf(logits[e] - mx);
        route_s = am;
        if (blockIdx.x == 0) {
            out_tail[0] = (float)am;      // route
            out_tail[1] = 1.0f / den;     // out_prob_max = exp(0)/den
        }
    }
    __syncthreads();
    const int r = route_s;

    const int i = blockIdx.x * 256 + t;   // 0 .. 32767
    if (i < 2 * HD * HD) {
        int o = i >> 7, k = i & 127;
        float v1 = (o < HD) ? uW1[o * HD + k] : eW1[r * HD * HD + (o - HD) * HD + k];
        W1c[i] = f2bf(v1);
        int o2 = i >> 8, j = i & 255;
        float v2 = (j < HD) ? uW2[o2 * HD + j] : eW2[r * HD * HD + o2 * HD + (j - HD)];
        W2c[i] = f2bf(v2);
    }
    if (i < 2 * HD) b1c[i] = (i < HD) ? ub1[i] : eb1[r * HD + (i - HD)];
    if (i < HD)     b2s[i] = ub2[i] + eb2[r * HD + i];
}

// ---------------- main: R15 structure + GEMM2 token-split (halved hs reads) ----------------
// GEMM1: wave w owns hidden cols [w*32, w*32+32), all 32 tokens (unchanged).
// GEMM2: wave w owns out cols [(w&3)*32, +32) x tokens [(w>>2)*16, +16):
//        one hs fragment read feeds TWO MFMAs -> hs reads 16 -> 8 per wave.
// Output via os (LDS) + fully-coalesced full-line nontemporal stores (R15 win).
__global__ __launch_bounds__(512, 4)
void moe_main(const float* __restrict__ x,
              const unsigned short* __restrict__ W1c, const unsigned short* __restrict__ W2c,
              const float* __restrict__ b1c, const float* __restrict__ b2s,
              float* __restrict__ out) {
    __shared__ __align__(16) unsigned short xs[BM * LDX];  //  8704 B
    __shared__ __align__(16) unsigned short hs[BM * LDH];  // 16896 B
    __shared__ __align__(16) float os[BM * LDO];           // 16896 B

    const int t = threadIdx.x;     // 0..511
    const int lane = t & 63;
    const int w = t >> 6;          // wave 0..7
    const int l16 = lane & 15;
    const int lq = lane >> 4;      // quadrant 0..3
    const int ncb = w * 32;        // GEMM1: this wave's 32 hidden cols
    const int cg = w & 3;          // GEMM2: col group (32 out cols at cg*32)
    const int th = w >> 2;         // GEMM2: token half (16 tokens at th*16)

    // ---- load this wave's weight fragments into registers (ONCE) ----
    bf16x8 w1[4][2];   // [ks][ht]      32 VGPR
    bf16x8 w2[8][2];   // [ks][ct]      64 VGPR (token-split: 32 cols/wave)
#pragma unroll
    for (int ks = 0; ks < 4; ++ks)
#pragma unroll
        for (int ht = 0; ht < 2; ++ht)
            w1[ks][ht] = *(const bf16x8*)&W1c[(ncb + ht * 16 + l16) * HD + ks * 32 + lq * 8];
#pragma unroll
    for (int ks = 0; ks < 8; ++ks)
#pragma unroll
        for (int ct = 0; ct < 2; ++ct)
            w2[ks][ct] = *(const bf16x8*)&W2c[(cg * 32 + ct * 16 + l16) * 256 + ks * 32 + lq * 8];

    f32x4 bias1v[2], bias2v[2];
#pragma unroll
    for (int ht = 0; ht < 2; ++ht) bias1v[ht] = *(const f32x4*)&b1c[ncb + ht * 16 + lq * 4];
#pragma unroll
    for (int ct = 0; ct < 2; ++ct) bias2v[ct] = *(const f32x4*)&b2s[cg * 32 + ct * 16 + lq * 4];

    // staging decomposition: 1024 float4-units / 512 threads = 2 per thread
    const int srow0 = t >> 5;            // 0..15
    const int sc4 = (t & 31) * 4;
    // output-store decomposition: rows t>>5 and 16+(t>>5), col chunk (t&31)*4
    const int orow = t >> 5;
    const int ocol = (t & 31) * 4;

    int tile = blockIdx.x;
    float4 pv[2];
    { // prefetch first tile
        const float4* x4 = (const float4*)(x + (size_t)tile * (BM * HD));
#pragma unroll
        for (int i = 0; i < 2; ++i) pv[i] = x4[t + i * 512];
    }

    while (tile < NTILES) {
        const int ntile = tile + GRID;

        // ---- stage prefetched x tile (f32 -> bf16, packed b64 writes) ----
#pragma unroll
        for (int i = 0; i < 2; ++i) {
            bf16x4 b;
            b[0] = (__bf16)pv[i].x; b[1] = (__bf16)pv[i].y;
            b[2] = (__bf16)pv[i].z; b[3] = (__bf16)pv[i].w;
            *(bf16x4*)&xs[(srow0 + i * 16) * LDX + sc4] = b;
        }

        // ---- issue next tile's loads; stay in flight across barriers ----
        if (ntile < NTILES) {
            const float4* x4 = (const float4*)(x + (size_t)ntile * (BM * HD));
#pragma unroll
            for (int i = 0; i < 2; ++i) pv[i] = x4[t + i * 512];
        }
        BAR();   // xs ready

        // ---- GEMM1 (swapped): Hmid^T slice = W1c[ncb..ncb+32) · X^T ----
        f32x4 acc1[2][2] = {};
#pragma unroll
        for (int ks = 0; ks < 4; ++ks) {
            const int kofs = ks * 32 + lq * 8;
            bf16x8 xf[2];
#pragma unroll
            for (int tt = 0; tt < 2; ++tt)
                xf[tt] = *(const bf16x8*)&xs[(tt * 16 + l16) * LDX + kofs];
#pragma unroll
            for (int ht = 0; ht < 2; ++ht)
#pragma unroll
                for (int tt = 0; tt < 2; ++tt)
                    acc1[ht][tt] = __builtin_amdgcn_mfma_f32_16x16x32_bf16(
                        w1[ks][ht], xf[tt], acc1[ht][tt], 0, 0, 0);
        }
        // bias + relu + packed b64 store of 4 consecutive hidden cols per token
#pragma unroll
        for (int ht = 0; ht < 2; ++ht)
#pragma unroll
            for (int tt = 0; tt < 2; ++tt) {
                bf16x4 hv;
#pragma unroll
                for (int r = 0; r < 4; ++r) {
                    float v = acc1[ht][tt][r] + bias1v[ht][r];
                    hv[r] = (__bf16)(v > 0.f ? v : 0.f);
                }
                *(bf16x4*)&hs[(tt * 16 + l16) * LDH + ncb + ht * 16 + lq * 4] = hv;
            }
        BAR();   // hs ready

        // ---- GEMM2 (token-split): out cols [cg*32,+32) x tokens [th*16,+16) ----
        // ONE hs fragment read per ks feeds TWO MFMAs.
        {
            f32x4 acc2[2] = {};
#pragma unroll
            for (int ks = 0; ks < 8; ++ks) {
                bf16x8 hf = *(const bf16x8*)&hs[(th * 16 + l16) * LDH + ks * 32 + lq * 8];
#pragma unroll
                for (int ct = 0; ct < 2; ++ct)
                    acc2[ct] = __builtin_amdgcn_mfma_f32_16x16x32_bf16(
                        w2[ks][ct], hf, acc2[ct], 0, 0, 0);
            }
#pragma unroll
            for (int ct = 0; ct < 2; ++ct) {
                f32x4 o;
#pragma unroll
                for (int r = 0; r < 4; ++r) o[r] = acc2[ct][r] + bias2v[ct][r];
                *(f32x4*)&os[(th * 16 + l16) * LDO + cg * 32 + ct * 16 + lq * 4] = o;
            }
        }
        BAR();   // os ready

        // ---- fully-coalesced nontemporal stores: 2 x 1KB-per-wave-instruction ----
        {
            float* outp = out + (size_t)tile * (BM * HD);
            f32x4 a = *(const f32x4*)&os[orow * LDO + ocol];
            f32x4 b = *(const f32x4*)&os[(16 + orow) * LDO + ocol];
            __builtin_nontemporal_store(a, (f32x4*)(outp + t * 4));
            __builtin_nontemporal_store(b, (f32x4*)(outp + 2048 + t * 4));
        }

        tile = ntile;
    }
}

extern "C" void kernel_launch(void* const* d_in, const int* in_sizes, int n_in,
                              void* d_out, int out_size, void* d_ws, size_t ws_size,
                              hipStream_t stream) {
    const float* x      = (const float*)d_in[0];
    const float* x_real = (const float*)d_in[1];
    // d_in[2] = user_embedding (unused by reference)
    const float* uW1 = (const float*)d_in[3];
    const float* ub1 = (const float*)d_in[4];
    const float* uW2 = (const float*)d_in[5];
    const float* ub2 = (const float*)d_in[6];
    const float* eW1 = (const float*)d_in[7];
    const float* eb1 = (const float*)d_in[8];
    const float* eW2 = (const float*)d_in[9];
    const float* eb2 = (const float*)d_in[10];
    const float* sW1 = (const float*)d_in[11];
    const float* sb1 = (const float*)d_in[12];
    const float* sW2 = (const float*)d_in[13];
    const float* sb2 = (const float*)d_in[14];
    float* out = (float*)d_out;

    char* ws = (char*)d_ws;
    unsigned short* W1c = (unsigned short*)(ws + 64);
    unsigned short* W2c = (unsigned short*)(ws + 64 + 65536);
    float* b1c = (float*)(ws + 64 + 131072);
    float* b2s = (float*)(ws + 64 + 131072 + 1024);

    prep_route<<<128, 256, 0, stream>>>(x_real, sW1, sb1, sW2, sb2,
                                        uW1, ub1, uW2, ub2, eW1, eb1, eW2, eb2,
                                        out + (size_t)BATCH * LSEQ * HD,
                                        W1c, W2c, b1c, b2s);
    moe_main<<<GRID, 512, 0, stream>>>(x, W1c, W2c, b1c, b2s, out);
}

// Round 17
// 81.216 us; speedup vs baseline: 2.2512x; 2.2512x over previous
//
#include <hip/hip_runtime.h>

#define HD 128
#define LSEQ 200
#define BATCH 2048
#define NE 8
#define SWH 64

#define BM 32        // tokens per tile
#define LDX 136      // padded bf16 row stride for x tile
#define LDH 264      // padded bf16 row stride for hidden tile
#define LDO 132      // padded f32 row stride for out tile
#define NTILES ((BATCH * LSEQ) / BM)   // 12800
#define GRID 512     // persistent: 2 blocks/CU (512 threads -> 16 waves/CU)
#define KITER 25     // 12800/512 tiles per block, uniform

typedef float f32x4 __attribute__((ext_vector_type(4)));
typedef __bf16 bf16x4 __attribute__((ext_vector_type(4)));
typedef __bf16 bf16x8 __attribute__((ext_vector_type(8)));

// Raw barrier: per-wave LDS drain + s_barrier, no vmcnt(0) drain.
#define BAR() do {                                          \
    asm volatile("s_waitcnt lgkmcnt(0)" ::: "memory");      \
    __builtin_amdgcn_sched_barrier(0);                      \
    __builtin_amdgcn_s_barrier();                           \
    __builtin_amdgcn_sched_barrier(0);                      \
} while (0)

static __device__ __forceinline__ unsigned short f2bf(float f) {
    union { float f; unsigned u; } v; v.f = f;
    unsigned u = v.u;
    u += 0x7fffu + ((u >> 16) & 1u);   // round-to-nearest-even
    return (unsigned short)(u >> 16);
}

// ---------------- fused routing + weight prep (R8 version, verbatim) ----------------
// W1c [256][128]: rows 0-127 = uW1, rows 128-255 = eW1[route]
// W2c [128][256]: cols 0-127 = uW2, cols 128-255 = eW2[route]
__global__ void prep_route(const float* __restrict__ x_real,
                           const float* __restrict__ sW1, const float* __restrict__ sb1,
                           const float* __restrict__ sW2, const float* __restrict__ sb2,
                           const float* __restrict__ uW1, const float* __restrict__ ub1,
                           const float* __restrict__ uW2, const float* __restrict__ ub2,
                           const float* __restrict__ eW1, const float* __restrict__ eb1,
                           const float* __restrict__ eW2, const float* __restrict__ eb2,
                           float* __restrict__ out_tail,
                           unsigned short* __restrict__ W1c, unsigned short* __restrict__ W2c,
                           float* __restrict__ b1c, float* __restrict__ b2s) {
    __shared__ float part[256];
    __shared__ float xm[HD];
    __shared__ float hsw[SWH];
    __shared__ float logits[NE];
    __shared__ int route_s;
    const int t = threadIdx.x;   // 256 threads

    {
        int col = t & 127, half = t >> 7;
        float s = 0.f;
        for (int l = half * 100; l < half * 100 + 100; ++l) s += x_real[l * HD + col];
        part[t] = s;
    }
    __syncthreads();
    if (t < HD) xm[t] = (part[t] + part[t + 128]) * (1.0f / LSEQ);
    __syncthreads();
    if (t < SWH) {
        float s = sb1[t];
        for (int k = 0; k < HD; ++k) s += xm[k] * sW1[t * HD + k];
        hsw[t] = s > 0.f ? s : 0.f;
    }
    __syncthreads();
    if (t < NE) {
        float s = sb2[t];
        for (int k = 0; k < SWH; ++k) s += hsw[k] * sW2[t * SWH + k];
        logits[t] = s;
    }
    __syncthreads();
    if (t == 0) {
        float mx = logits[0]; int am = 0;
        for (int e = 1; e < NE; ++e) if (logits[e] > mx) { mx = logits[e]; am = e; }
        float den = 0.f;
        for (int e = 0; e < NE; ++e) den += __expf(logits[e] - mx);
        route_s = am;
        if (blockIdx.x == 0) {
            out_tail[0] = (float)am;      // route
            out_tail[1] = 1.0f / den;     // out_prob_max = exp(0)/den
        }
    }
    __syncthreads();
    const int r = route_s;

    const int i = blockIdx.x * 256 + t;   // 0 .. 32767
    if (i < 2 * HD * HD) {
        int o = i >> 7, k = i & 127;
        float v1 = (o < HD) ? uW1[o * HD + k] : eW1[r * HD * HD + (o - HD) * HD + k];
        W1c[i] = f2bf(v1);
        int o2 = i >> 8, j = i & 255;
        float v2 = (j < HD) ? uW2[o2 * HD + j] : eW2[r * HD * HD + o2 * HD + (j - HD)];
        W2c[i] = f2bf(v2);
    }
    if (i < 2 * HD) b1c[i] = (i < HD) ? ub1[i] : eb1[r * HD + (i - HD)];
    if (i < HD)     b2s[i] = ub2[i] + eb2[r * HD + i];
}

// ---------------- main: R15 base + 2-phase skewed pipeline ----------------
// P1: GEMM1(tile i) [xs[i&1] -> hs]  ||  store os(tile i-1) -> global (NT, coalesced)
//     ||  stage xs[(i+1)&1] <- pv.       BAR.
// P2: GEMM2(tile i) [hs -> os]  ||  issue pv <- tile i+2.                 BAR.
// Weight fragments in registers (R15 org: w1 32 + w2 32 VGPR). LDS 51.2 KB.
__global__ __launch_bounds__(512, 4)
void moe_main(const float* __restrict__ x,
              const unsigned short* __restrict__ W1c, const unsigned short* __restrict__ W2c,
              const float* __restrict__ b1c, const float* __restrict__ b2s,
              float* __restrict__ out) {
    __shared__ __align__(16) unsigned short xs[2][BM * LDX];  // 2 x 8704 B
    __shared__ __align__(16) unsigned short hs[BM * LDH];     // 16896 B
    __shared__ __align__(16) float os[BM * LDO];              // 16896 B

    const int t = threadIdx.x;     // 0..511
    const int lane = t & 63;
    const int w = t >> 6;          // wave 0..7
    const int l16 = lane & 15;
    const int lq = lane >> 4;      // quadrant 0..3
    const int ncb = w * 32;        // GEMM1: this wave's 32 hidden cols
    const int ncb2 = w * 16;       // GEMM2: this wave's 16 output cols

    // ---- load this wave's weight fragments into registers (ONCE) ----
    bf16x8 w1[4][2];   // [ks][ht]  32 VGPR
    bf16x8 w2[8];      // [ks]      32 VGPR
#pragma unroll
    for (int ks = 0; ks < 4; ++ks)
#pragma unroll
        for (int ht = 0; ht < 2; ++ht)
            w1[ks][ht] = *(const bf16x8*)&W1c[(ncb + ht * 16 + l16) * HD + ks * 32 + lq * 8];
#pragma unroll
    for (int ks = 0; ks < 8; ++ks)
        w2[ks] = *(const bf16x8*)&W2c[(ncb2 + l16) * 256 + ks * 32 + lq * 8];

    f32x4 bias1v[2], bias2v;
#pragma unroll
    for (int ht = 0; ht < 2; ++ht) bias1v[ht] = *(const f32x4*)&b1c[ncb + ht * 16 + lq * 4];
    bias2v = *(const f32x4*)&b2s[ncb2 + lq * 4];

    // staging decomposition: 1024 float4-units / 512 threads = 2 per thread
    const int srow0 = t >> 5;            // 0..15
    const int sc4 = (t & 31) * 4;
    // output-store decomposition
    const int orow = t >> 5;
    const int ocol = (t & 31) * 4;

    const int t0 = blockIdx.x;
    float4 pv[2];

    // ---- prologue: pv <- tile0; stage xs[0] <- tile0; pv <- tile1 ----
    {
        const float4* x4 = (const float4*)(x + (size_t)t0 * (BM * HD));
        pv[0] = x4[t]; pv[1] = x4[t + 512];
#pragma unroll
        for (int i = 0; i < 2; ++i) {
            bf16x4 b;
            b[0] = (__bf16)pv[i].x; b[1] = (__bf16)pv[i].y;
            b[2] = (__bf16)pv[i].z; b[3] = (__bf16)pv[i].w;
            *(bf16x4*)&xs[0][(srow0 + i * 16) * LDX + sc4] = b;
        }
        const float4* x4b = (const float4*)(x + (size_t)(t0 + GRID) * (BM * HD));
        pv[0] = x4b[t]; pv[1] = x4b[t + 512];
    }
    BAR();

    for (int i = 0; i < KITER; ++i) {
        const int tile = t0 + i * GRID;
        const unsigned short* xsr = xs[i & 1];
        unsigned short* xsw = xs[(i + 1) & 1];

        // ================= P1 =================
        // store os (tile i-1) -> global: fully-coalesced NT full lines
        if (i >= 1) {
            float* outp = out + (size_t)(tile - GRID) * (BM * HD);
            f32x4 a = *(const f32x4*)&os[orow * LDO + ocol];
            f32x4 b = *(const f32x4*)&os[(16 + orow) * LDO + ocol];
            __builtin_nontemporal_store(a, (f32x4*)(outp + t * 4));
            __builtin_nontemporal_store(b, (f32x4*)(outp + 2048 + t * 4));
        }
        // stage xs[(i+1)&1] <- pv (tile i+1)
        if (i <= KITER - 2) {
#pragma unroll
            for (int j = 0; j < 2; ++j) {
                bf16x4 b;
                b[0] = (__bf16)pv[j].x; b[1] = (__bf16)pv[j].y;
                b[2] = (__bf16)pv[j].z; b[3] = (__bf16)pv[j].w;
                *(bf16x4*)&xsw[(srow0 + j * 16) * LDX + sc4] = b;
            }
        }
        // GEMM1 (swapped): Hmid^T slice = W1c[ncb..ncb+32) · X^T
        {
            f32x4 acc1[2][2] = {};
#pragma unroll
            for (int ks = 0; ks < 4; ++ks) {
                const int kofs = ks * 32 + lq * 8;
                bf16x8 xf[2];
#pragma unroll
                for (int tt = 0; tt < 2; ++tt)
                    xf[tt] = *(const bf16x8*)&xsr[(tt * 16 + l16) * LDX + kofs];
#pragma unroll
                for (int ht = 0; ht < 2; ++ht)
#pragma unroll
                    for (int tt = 0; tt < 2; ++tt)
                        acc1[ht][tt] = __builtin_amdgcn_mfma_f32_16x16x32_bf16(
                            w1[ks][ht], xf[tt], acc1[ht][tt], 0, 0, 0);
            }
#pragma unroll
            for (int ht = 0; ht < 2; ++ht)
#pragma unroll
                for (int tt = 0; tt < 2; ++tt) {
                    bf16x4 hv;
#pragma unroll
                    for (int r = 0; r < 4; ++r) {
                        float v = acc1[ht][tt][r] + bias1v[ht][r];
                        hv[r] = (__bf16)(v > 0.f ? v : 0.f);
                    }
                    *(bf16x4*)&hs[(tt * 16 + l16) * LDH + ncb + ht * 16 + lq * 4] = hv;
                }
        }
        BAR();   // hs ready; os consumed; xs[(i+1)&1] ready

        // ================= P2 =================
        // issue pv <- tile i+2 (in flight across BAR2, consumed P1(i+1)... P1(i+2))
        if (i <= KITER - 3) {
            const float4* x4n = (const float4*)(x + (size_t)(tile + 2 * GRID) * (BM * HD));
            pv[0] = x4n[t]; pv[1] = x4n[t + 512];
        }
        // GEMM2 (swapped): out^T slice = W2c[ncb2..ncb2+16) · Hmid^T -> os
#pragma unroll
        for (int tt = 0; tt < 2; ++tt) {
            f32x4 acc2 = {};
#pragma unroll
            for (int ks = 0; ks < 8; ++ks) {
                bf16x8 hf = *(const bf16x8*)&hs[(tt * 16 + l16) * LDH + ks * 32 + lq * 8];
                acc2 = __builtin_amdgcn_mfma_f32_16x16x32_bf16(w2[ks], hf, acc2, 0, 0, 0);
            }
            f32x4 o;
#pragma unroll
            for (int r = 0; r < 4; ++r) o[r] = acc2[r] + bias2v[r];
            *(f32x4*)&os[(tt * 16 + l16) * LDO + ncb2 + lq * 4] = o;
        }
        BAR();   // os ready for next P1's store
    }

    // ---- epilogue: store last tile's os ----
    {
        float* outp = out + (size_t)(t0 + (KITER - 1) * GRID) * (BM * HD);
        f32x4 a = *(const f32x4*)&os[orow * LDO + ocol];
        f32x4 b = *(const f32x4*)&os[(16 + orow) * LDO + ocol];
        __builtin_nontemporal_store(a, (f32x4*)(outp + t * 4));
        __builtin_nontemporal_store(b, (f32x4*)(outp + 2048 + t * 4));
    }
}

extern "C" void kernel_launch(void* const* d_in, const int* in_sizes, int n_in,
                              void* d_out, int out_size, void* d_ws, size_t ws_size,
                              hipStream_t stream) {
    const float* x      = (const float*)d_in[0];
    const float* x_real = (const float*)d_in[1];
    // d_in[2] = user_embedding (unused by reference)
    const float* uW1 = (const float*)d_in[3];
    const float* ub1 = (const float*)d_in[4];
    const float* uW2 = (const float*)d_in[5];
    const float* ub2 = (const float*)d_in[6];
    const float* eW1 = (const float*)d_in[7];
    const float* eb1 = (const float*)d_in[8];
    const float* eW2 = (const float*)d_in[9];
    const float* eb2 = (const float*)d_in[10];
    const float* sW1 = (const float*)d_in[11];
    const float* sb1 = (const float*)d_in[12];
    const float* sW2 = (const float*)d_in[13];
    const float* sb2 = (const float*)d_in[14];
    float* out = (float*)d_out;

    char* ws = (char*)d_ws;
    unsigned short* W1c = (unsigned short*)(ws + 64);
    unsigned short* W2c = (unsigned short*)(ws + 64 + 65536);
    float* b1c = (float*)(ws + 64 + 131072);
    float* b2s = (float*)(ws + 64 + 131072 + 1024);

    prep_route<<<128, 256, 0, stream>>>(x_real, sW1, sb1, sW2, sb2,
                                        uW1, ub1, uW2, ub2, eW1, eb1, eW2, eb2,
                                        out + (size_t)BATCH * LSEQ * HD,
                                        W1c, W2c, b1c, b2s);
    moe_main<<<GRID, 512, 0, stream>>>(x, W1c, W2c, b1c, b2s, out);
}